// Round 7
// baseline (197.919 us; speedup 1.0000x reference)
//
#include <hip/hip_runtime.h>

// ---------------------------------------------------------------------------
// SelfAttention, L=2048, E=1024, H=16, D=64. fp32 in/out, bf16 MFMA compute.
//   cvt_all   : f32->bf16 (q,k,v,W*) + bias pre-SWIZZLED to MFMA-D fragment
//               order + out=bo prefill (bias swizzle: 8x fewer L2
//               transactions; round-4 win).
//   gemm_pd<0>: Q,K,V projections (z selects tensor; z=2 writes V^T)
//   flash9    : split-K flash, S^T softmax, register-resident P, 2-TILE
//               SOFTWARE PIPELINE: PV(t-1) runs from registers at the top of
//               tile t, overlapping S(t)'s ds_reads + exp chain (the serial
//               chain 4 waves/SIMD couldn't cover; MfmaUtil 19/VALU 30).
//   merge_attn: sum 4 partials, divide, write bf16 AO
//   gemm_pd<2>: out += AO @ Wo^T, split-K=2, unsafeAtomicAdd f32
// LESSONS: (256,8) = 64-reg cap = spill storm (r5, 1.2GB scratch HBM).
// OSPLIT=4 = 4x atomic traffic = ~8-10us (r4/r6). Occupancy is NOT the flash
// lever (r2); LDS-pipe (r2->r3) and VMEM divergence (r4) were; chain is next.
// ---------------------------------------------------------------------------

#define L_SEQ 2048
#define E_DIM 1024
#define H_HEADS 16
#define D_HEAD 64
#define KSPLIT 4     // flash k-split (1024 blocks = 4/CU; reg-footprint cap)
#define OSPLIT 2     // out-proj k-split

typedef unsigned short u16;
typedef unsigned int u32;
typedef __attribute__((ext_vector_type(8))) short bf16x8;
typedef __attribute__((ext_vector_type(4))) short bf16x4;
typedef __attribute__((ext_vector_type(8))) unsigned short u16x8;
typedef __attribute__((ext_vector_type(4))) unsigned short u16x4;
typedef __attribute__((ext_vector_type(4))) float f32x4;

#define C_LOG2E_32 0.045084220027780106f   // log2(e)/32

__device__ __forceinline__ float bf2f(u16 u) {
  union { u32 i; float f; } v; v.i = ((u32)u) << 16; return v.f;
}
__device__ __forceinline__ u16 f2bf(float f) {
  union { float f; u32 i; } v; v.f = f;
  u32 u = v.i;
  u += 0x7FFFu + ((u >> 16) & 1u);   // RNE
  return (u16)(u >> 16);
}
// pack bf16(lo), bf16(hi) into one u32 (round-half-up; operands > 0)
__device__ __forceinline__ u32 pack_bf16_pair(float lo, float hi) {
  union { float f; u32 u; } a, b;
  a.f = lo; b.f = hi;
  return __builtin_amdgcn_perm(b.u + 0x8000u, a.u + 0x8000u, 0x07060302u);
}
// async global->LDS 16B/lane; LDS dest = (wave-uniform base) + lane*16
__device__ __forceinline__ void gload16(const u16* g, u16* l) {
  __builtin_amdgcn_global_load_lds(
      (const __attribute__((address_space(1))) u32*)g,
      (__attribute__((address_space(3))) u32*)l, 16, 0, 0);
}

// ---------------------------------------------------------------------------
// One-shot conversion + bias fragment-swizzle + out prefill.
// Bias: thread = (tile, lane); tile = l16*128 + q16; lane reads
// dist[q16*16+col][l16*16+quad*4..+3] (f32x4) and writes u16x4 at
// Bp[tile*256 + lane*4] -- exactly the 16x16x32 MFMA D-fragment order.
// ---------------------------------------------------------------------------
__global__ void cvt_all(const float* __restrict__ xq, const float* __restrict__ xk,
                        const float* __restrict__ xv,
                        const float* __restrict__ wq, const float* __restrict__ wk,
                        const float* __restrict__ wv, const float* __restrict__ wo,
                        const float* __restrict__ dist, const float* __restrict__ bo,
                        u16* oq, u16* ok, u16* ov,
                        u16* owq, u16* owk, u16* owv, u16* owo, u16* obias,
                        float* __restrict__ outp)
{
  size_t gid = (size_t)blockIdx.x * 256 + threadIdx.x;
  const size_t NQ = 262144;     // (L*E)/8
  const size_t NW = 131072;     // (E*E)/8
  const size_t DL2 = 1048576;   // (L*L)/4 bias quads
  const size_t FILL = DL2 + 3 * NQ + 4 * NW;   // 2359296

  if (gid < DL2) {              // bias: fragment-swizzled layout
    int tile = (int)(gid >> 6);
    int ln   = (int)(gid & 63);
    int l16  = tile >> 7;       // tile = l16*128 + q16  (L/16 = 128)
    int q16  = tile & 127;
    int qq = q16 * 16 + (ln & 15);
    int ll = l16 * 16 + (ln >> 4) * 4;
    f32x4 d4 = *(const f32x4*)&dist[(size_t)qq * L_SEQ + ll];
    u16x4 o4;
#pragma unroll
    for (int j = 0; j < 4; ++j) {
      float f = d4[j];
      f = (f == 0.f) ? 0.f : C_LOG2E_32 / (f + 1.f);
      o4[j] = f2bf(f);
    }
    *(u16x4*)&obias[(size_t)tile * 256 + ln * 4] = o4;
    return;
  }

  if (gid >= FILL) {            // out[q][:] = bo (out-proj accumulates on top)
    size_t off = (gid - FILL) * 8;
    int n = (int)(off & (E_DIM - 1));
    *(f32x4*)&outp[off] = *(const f32x4*)&bo[n];
    *(f32x4*)&outp[off + 4] = *(const f32x4*)&bo[n + 4];
    return;
  }

  size_t g = gid - DL2;
  const float* src; u16* dst; size_t off;
  if      (g <     NQ)           { src = xq;   dst = oq;    off = g; }
  else if (g < 2 * NQ)           { src = xk;   dst = ok;    off = g - NQ; }
  else if (g < 3 * NQ)           { src = xv;   dst = ov;    off = g - 2 * NQ; }
  else if (g < 3 * NQ + NW)      { src = wq;   dst = owq;   off = g - 3 * NQ; }
  else if (g < 3 * NQ + 2 * NW)  { src = wk;   dst = owk;   off = g - 3 * NQ - NW; }
  else if (g < 3 * NQ + 3 * NW)  { src = wv;   dst = owv;   off = g - 3 * NQ - 2 * NW; }
  else                           { src = wo;   dst = owo;   off = g - 3 * NQ - 3 * NW; }

  f32x4 v0 = *(const f32x4*)&src[off * 8];
  f32x4 v1 = *(const f32x4*)&src[off * 8 + 4];
  u16x8 o;
#pragma unroll
  for (int j = 0; j < 4; ++j) {
    o[j] = f2bf(v0[j]); o[j + 4] = f2bf(v1[j]);
  }
  *(u16x8*)&dst[off * 8] = o;
}

// ---------------------------------------------------------------------------
// NT GEMM, bf16, pipelined: C[M,N] = A[M,K]*B[N,K]^T.
// 128x128 tile, BK=32, double-buffered LDS (32 KB), one barrier/iter,
// prefetch after barrier. LDS slot s of row r holds granule s^((r>>1)&3).
// OUTMODE 0: triple (z selects A/B/C), bf16 out, z==2 writes C^T.
// OUTMODE 2: single tensor, z = K-split (K/OSPLIT each), f32 atomic-add out.
// ---------------------------------------------------------------------------
#define TM 128
#define TN 128
#define BK 32

template<int OUTMODE>
__global__ __launch_bounds__(256, 3) void gemm_pd(
    const u16* __restrict__ A0, const u16* __restrict__ B0, void* __restrict__ C0,
    const u16* __restrict__ A1, const u16* __restrict__ B1, void* __restrict__ C1,
    const u16* __restrict__ A2, const u16* __restrict__ B2, void* __restrict__ C2,
    int M, int N, int K)
{
  const u16* A; const u16* B; void* C;
  if (OUTMODE == 2)         { A = A0; B = B0; C = C0; }
  else if (blockIdx.z == 0) { A = A0; B = B0; C = C0; }
  else if (blockIdx.z == 1) { A = A1; B = B1; C = C1; }
  else                      { A = A2; B = B2; C = C2; }

  __shared__ __align__(16) u16 As[2][TM * BK];   // 8 KB per buf
  __shared__ __align__(16) u16 Bs[2][TN * BK];

  const int m0 = blockIdx.y * TM;
  const int n0 = blockIdx.x * TN;
  const int t = threadIdx.x;
  const int wave = t >> 6;
  const int lane = t & 63;
  const int quad = lane >> 4;
  const int col  = lane & 15;
  const int wm = (wave >> 1) * 64;
  const int wn = (wave & 1) * 64;

  // staging: one gload16 covers 16 rows x 32 cols; lane -> row lane/4,
  // slot lane&3, global granule (lane&3)^((lane>>3)&3)
  const int sr = lane >> 2;
  const int sg = ((lane & 3) ^ ((lane >> 3) & 3)) * 8;
  const u16* gA = A + (size_t)(m0 + wave * 32 + sr) * K + sg;
  const u16* gB = B + (size_t)(n0 + wave * 32 + sr) * K + sg;
  const int lo0 = (wave * 32) * BK;
  const int lo1 = (wave * 32 + 16) * BK;

  const int kbeg = (OUTMODE == 2) ? blockIdx.z * (K / OSPLIT) : 0;
  const int kend = (OUTMODE == 2) ? kbeg + K / OSPLIT : K;

  f32x4 acc[4][4];
#pragma unroll
  for (int i = 0; i < 4; ++i)
#pragma unroll
    for (int j = 0; j < 4; ++j) acc[i][j] = (f32x4){0.f, 0.f, 0.f, 0.f};

  // prologue: stage first tile into buf 0
  gload16(gA + kbeg, &As[0][lo0]);
  gload16(gA + (size_t)16 * K + kbeg, &As[0][lo1]);
  gload16(gB + kbeg, &Bs[0][lo0]);
  gload16(gB + (size_t)16 * K + kbeg, &Bs[0][lo1]);

  const int slot8 = (quad ^ ((col >> 1) & 3)) * 8;   // frag granule (swizzled)

  int buf = 0;
  for (int k0 = kbeg; k0 < kend; k0 += BK) {
    __syncthreads();   // tile(buf) visible; prev iter's LDS reads done
    int nk = k0 + BK;
    if (nk < kend) {   // prefetch next tile; in flight across whole compute
      gload16(gA + nk, &As[buf ^ 1][lo0]);
      gload16(gA + (size_t)16 * K + nk, &As[buf ^ 1][lo1]);
      gload16(gB + nk, &Bs[buf ^ 1][lo0]);
      gload16(gB + (size_t)16 * K + nk, &Bs[buf ^ 1][lo1]);
    }

    bf16x8 af[4], bfr[4];
#pragma unroll
    for (int i = 0; i < 4; ++i)
      af[i] = *(const bf16x8*)&As[buf][(wm + i * 16 + col) * BK + slot8];
#pragma unroll
    for (int j = 0; j < 4; ++j)
      bfr[j] = *(const bf16x8*)&Bs[buf][(wn + j * 16 + col) * BK + slot8];

#pragma unroll
    for (int i = 0; i < 4; ++i)
#pragma unroll
      for (int j = 0; j < 4; ++j)
        acc[i][j] = __builtin_amdgcn_mfma_f32_16x16x32_bf16(af[i], bfr[j], acc[i][j], 0, 0, 0);

    buf ^= 1;
  }

  const bool transC = (OUTMODE == 0) && (blockIdx.z == 2);
#pragma unroll
  for (int i = 0; i < 4; ++i) {
    int rowb = m0 + wm + i * 16 + quad * 4;
#pragma unroll
    for (int j = 0; j < 4; ++j) {
      int cn = n0 + wn + j * 16 + col;
      if (OUTMODE == 2) {
#pragma unroll
        for (int r = 0; r < 4; ++r)
          unsafeAtomicAdd(&((float*)C)[(size_t)(rowb + r) * N + cn], acc[i][j][r]);
      } else if (transC) {
        u16x4 pk;
#pragma unroll
        for (int r = 0; r < 4; ++r) pk[r] = f2bf(acc[i][j][r]);
        *(u16x4*)&((u16*)C)[(size_t)cn * M + rowb] = pk;   // C^T: 4 contiguous
      } else {
#pragma unroll
        for (int r = 0; r < 4; ++r)
          ((u16*)C)[(size_t)(rowb + r) * N + cn] = f2bf(acc[i][j][r]);
      }
    }
  }
}

// ---------------------------------------------------------------------------
// Split-K flash attention, S^T form, register-resident P, 2-TILE PIPELINE.
// 32 q/wave (2 strips of 16), 128 q/block, grid 16x16x4 = 1024 blocks (4/CU).
// Per tile t: barrier -> prefetch(t+1) -> PV(t-1) from REGISTERS (pa_prev,
// vf_prev; independent of tile t's loads -> MFMA pipe busy under K ds_read
// latency + exp VALU chain) -> S(t) MFMA -> exp -> pack pa_cur -> read V(t)
// frags to vf_cur. V(t-1) lives in regs, so prefetch(t+1) overwriting the
// t-1 LDS buffer is race-free. Drain PV after the loop. Ping-pong register
// sets via macro (static names, no runtime indexing). ~+24 VGPR vs flash8;
// (256,4) budget 128 holds.
// Bias: fragment-swizzled Bp, 512B contiguous per wave-load (round-4 win).
// LDS/block = Ks 8K + Vs 8K = 16KB.
// ---------------------------------------------------------------------------
#define FK 32

__global__ __launch_bounds__(256, 4) void flash9(
    const u16* __restrict__ Q, const u16* __restrict__ Kp,
    const u16* __restrict__ Vt, const u16* __restrict__ Bb,
    u16* __restrict__ Op, float* __restrict__ lp)
{
  __shared__ __align__(16) u16 Ks[2][FK * 64];      // K-tile [l][d], swizzled
  __shared__ __align__(16) u16 Vs[2][D_HEAD * FK];  // V^T tile [d][l], swizzled

  const int h  = blockIdx.y;
  const int q0 = blockIdx.x * 128;
  const int z  = blockIdx.z;
  const int hoff = h * D_HEAD;
  const int kbase = z * (L_SEQ / KSPLIT);
  const int NT = (L_SEQ / KSPLIT) / FK;   // 16 tiles (even -> clean ping-pong)
  const int t = threadIdx.x;
  const int wave = t >> 6;
  const int lane = t & 63;
  const int quad = lane >> 4;
  const int col  = lane & 15;

  // Q fragments per strip (B-operand of S^T: n = q = col, k = d)
  bf16x8 qf[2][2];
#pragma unroll
  for (int s = 0; s < 2; ++s) {
    const int qs = q0 + wave * 32 + s * 16;
    const u16* qrow = Q + (size_t)(qs + col) * E_DIM + hoff;
    qf[s][0] = *(const bf16x8*)(qrow + quad * 8);
    qf[s][1] = *(const bf16x8*)(qrow + 32 + quad * 8);
  }
  // bias tile indexing: q16 block of this wave's strips, lane elem offset
  const int qb0 = blockIdx.x * 8 + wave * 2;   // (q0 + wave*32)/16
  const int lb4 = lane * 4;

  // K staging: 32 rows x 8 granules; wave covers 8 rows.
  const int krow = wave * 8 + (lane >> 3);
  const int kg = ((lane & 7) ^ (lane >> 3)) * 8;
  const u16* gK = Kp + (size_t)krow * E_DIM + hoff + kg;
  // V staging: 64 rows x 4 granules; wave covers 16 rows.
  const int vrow = wave * 16 + (lane >> 2);
  const int vg = ((lane & 3) ^ ((lane >> 4) & 3)) * 8;
  const u16* gV = Vt + (size_t)(hoff + vrow) * L_SEQ + vg;

  float l_lane[2] = {0.f, 0.f};
  f32x4 oacc[2][4];
#pragma unroll
  for (int s = 0; s < 2; ++s)
#pragma unroll
    for (int td = 0; td < 4; ++td) oacc[s][td] = (f32x4){0.f, 0.f, 0.f, 0.f};

  // prologue: stage tile 0 + bias regs for tile 0
  gload16(gK + (size_t)kbase * E_DIM, &Ks[0][wave * 8 * 64]);
  gload16(gV + kbase, &Vs[0][wave * 16 * FK]);
  u16x4 bv[2][2], bn[2][2];
  {
    const int kb16 = kbase >> 4;
#pragma unroll
    for (int s = 0; s < 2; ++s) {
      bv[s][0] = *(const u16x4*)&Bb[((size_t)(kb16 + 0) * 128 + qb0 + s) * 256 + lb4];
      bv[s][1] = *(const u16x4*)&Bb[((size_t)(kb16 + 1) * 128 + qb0 + s) * 256 + lb4];
    }
  }

  const int ks0 = (quad ^ (col & 7)) * 8;          // K frag slots (swizzled)
  const int ks1 = ((quad + 4) ^ (col & 7)) * 8;
  // V frag: row d = td*16+col; slot = (tt*2+(quad>>1)) ^ ((col>>2)&3)
  const int vc2 = (col >> 2) & 3;
  const int vq1 = quad >> 1;
  const int vlo = (quad & 1) * 4;

  // Ping-pong register state: pa = packed P (A-operand of PV), vf = V frags.
  bf16x4 pa0[2][2], pa1[2][2], vf0[2][4], vf1[2][4];

  int buf = 0;

  // One pipeline step for tile kt_: PV(prev tile) from PP/VP regs, then
  // S(kt_) -> exp -> PC, then V(kt_) frags -> VC.
#define FSTEP(kt_, PP, VP, PC, VC)                                            \
  {                                                                           \
    const int k0_ = kbase + (kt_) * FK;                                       \
    __syncthreads();   /* tile(buf) staged; prev LDS reads done */            \
    if ((kt_) + 1 < NT) {   /* prefetch next tile + next bias regs */         \
      const int nk_ = k0_ + FK;                                               \
      gload16(gK + (size_t)nk_ * E_DIM, &Ks[buf ^ 1][wave * 8 * 64]);         \
      gload16(gV + nk_, &Vs[buf ^ 1][wave * 16 * FK]);                        \
      const int nk16_ = nk_ >> 4;                                             \
      _Pragma("unroll")                                                       \
      for (int s = 0; s < 2; ++s) {                                           \
        bn[s][0] = *(const u16x4*)&Bb[((size_t)(nk16_ + 0) * 128 + qb0 + s) * 256 + lb4]; \
        bn[s][1] = *(const u16x4*)&Bb[((size_t)(nk16_ + 1) * 128 + qb0 + s) * 256 + lb4]; \
      }                                                                       \
    }                                                                         \
    const u16* Kb = &Ks[buf][0];                                              \
    const u16* Vb = &Vs[buf][0];                                              \
    /* PV of PREVIOUS tile: pure-register MFMA, fills pipe under loads */     \
    if ((kt_) > 0) {                                                          \
      _Pragma("unroll")                                                       \
      for (int s = 0; s < 2; ++s)                                             \
        _Pragma("unroll")                                                     \
        for (int td = 0; td < 4; ++td) {                                      \
          oacc[s][td] = __builtin_amdgcn_mfma_f32_16x16x16bf16_1k(            \
              PP[s][0], VP[0][td], oacc[s][td], 0, 0, 0);                     \
          oacc[s][td] = __builtin_amdgcn_mfma_f32_16x16x16bf16_1k(            \
              PP[s][1], VP[1][td], oacc[s][td], 0, 0, 0);                     \
        }                                                                     \
    }                                                                         \
    /* S^T(kt_): A = K-frag (m=l), B = Q-frag (n=q); D: l=quad*4+r, q=col */  \
    _Pragma("unroll")                                                         \
    for (int tt = 0; tt < 2; ++tt) {                                          \
      const u16* kr = &Kb[(tt * 16 + col) * 64];                              \
      bf16x8 kf0 = *(const bf16x8*)&kr[ks0];                                  \
      bf16x8 kf1 = *(const bf16x8*)&kr[ks1];                                  \
      _Pragma("unroll")                                                       \
      for (int s = 0; s < 2; ++s) {                                           \
        f32x4 a = (f32x4){0.f, 0.f, 0.f, 0.f};                                \
        a = __builtin_amdgcn_mfma_f32_16x16x32_bf16(kf0, qf[s][0], a, 0, 0, 0); \
        a = __builtin_amdgcn_mfma_f32_16x16x32_bf16(kf1, qf[s][1], a, 0, 0, 0); \
        float p[4];                                                           \
        _Pragma("unroll")                                                     \
        for (int r = 0; r < 4; ++r) {                                         \
          p[r] = __builtin_amdgcn_exp2f(fmaf(a[r], C_LOG2E_32, bf2f(bv[s][tt][r]))); \
          l_lane[s] += p[r];                                                  \
        }                                                                     \
        union { u32 w[2]; bf16x4 v; } pk_;                                    \
        pk_.w[0] = pack_bf16_pair(p[0], p[1]);                                \
        pk_.w[1] = pack_bf16_pair(p[2], p[3]);                                \
        PC[s][tt] = pk_.v;                                                    \
      }                                                                       \
    }                                                                         \
    /* V(kt_) frags -> regs (consumed by PV at tile kt_+1) */                 \
    _Pragma("unroll")                                                         \
    for (int tt = 0; tt < 2; ++tt) {                                          \
      const int slot_ = (tt * 2 + vq1) ^ vc2;                                 \
      _Pragma("unroll")                                                       \
      for (int td = 0; td < 4; ++td)                                          \
        VC[tt][td] = *(const bf16x4*)&Vb[(td * 16 + col) * FK + slot_ * 8 + vlo]; \
    }                                                                         \
    _Pragma("unroll")                                                         \
    for (int s = 0; s < 2; ++s) { bv[s][0] = bn[s][0]; bv[s][1] = bn[s][1]; } \
    buf ^= 1;                                                                 \
  }

  for (int kt = 0; kt < NT; kt += 2) {
    FSTEP(kt,     pa1, vf1, pa0, vf0);   // PV(kt-1) | build tile kt   state
    FSTEP(kt + 1, pa0, vf0, pa1, vf1);   // PV(kt)   | build tile kt+1 state
  }
#undef FSTEP

  // drain: PV of the last tile (NT-1), state in pa1/vf1
#pragma unroll
  for (int s = 0; s < 2; ++s)
#pragma unroll
    for (int td = 0; td < 4; ++td) {
      oacc[s][td] = __builtin_amdgcn_mfma_f32_16x16x16bf16_1k(
          pa1[s][0], vf1[0][td], oacc[s][td], 0, 0, 0);
      oacc[s][td] = __builtin_amdgcn_mfma_f32_16x16x16bf16_1k(
          pa1[s][1], vf1[1][td], oacc[s][td], 0, 0, 0);
    }

  // l reduction: lanes sharing (lane&15) hold partials across quads
#pragma unroll
  for (int s = 0; s < 2; ++s) {
    l_lane[s] += __shfl_xor(l_lane[s], 16);
    l_lane[s] += __shfl_xor(l_lane[s], 32);
    if (lane < 16)
      lp[((size_t)z * L_SEQ + q0 + wave * 32 + s * 16 + lane) * H_HEADS + h] = l_lane[s];
  }

#pragma unroll
  for (int s = 0; s < 2; ++s) {
    const int qrow_mine = q0 + wave * 32 + s * 16 + quad * 4;
#pragma unroll
    for (int td = 0; td < 4; ++td)
#pragma unroll
      for (int r = 0; r < 4; ++r)
        Op[((size_t)z * L_SEQ + qrow_mine + r) * E_DIM + hoff + td * 16 + col] = f2bf(oacc[s][td][r]);
  }
}

// ---------------------------------------------------------------------------
// Merge split-K partials: AO = (sum_s O_s) / (sum_s l_s), bf16 out.
// ---------------------------------------------------------------------------
__global__ void merge_attn(const u16* __restrict__ Op, const float* __restrict__ lp,
                           u16* __restrict__ AOb)
{
  size_t gid = (size_t)blockIdx.x * 256 + threadIdx.x;
  size_t idx = gid * 4;
  int q = (int)(idx >> 10);
  int e = (int)(idx & 1023);
  int h = e >> 6;
  float o[4] = {0.f, 0.f, 0.f, 0.f};
  float lsum = 0.f;
#pragma unroll
  for (int s = 0; s < KSPLIT; ++s) {
    u16x4 pv = *(const u16x4*)&Op[((size_t)s * L_SEQ + q) * E_DIM + e];
#pragma unroll
    for (int j = 0; j < 4; ++j) o[j] += bf2f(pv[j]);
    lsum += lp[((size_t)s * L_SEQ + q) * H_HEADS + h];
  }
  float inv = 1.f / lsum;
  u16x4 pk;
#pragma unroll
  for (int j = 0; j < 4; ++j) pk[j] = f2bf(o[j] * inv);
  *(u16x4*)&AOb[idx] = pk;
}

// ---------------------------------------------------------------------------
extern "C" void kernel_launch(void* const* d_in, const int* in_sizes, int n_in,
                              void* d_out, int out_size, void* d_ws, size_t ws_size,
                              hipStream_t stream)
{
  const float* values = (const float*)d_in[0];
  const float* keys   = (const float*)d_in[1];
  const float* query  = (const float*)d_in[2];
  const float* dist   = (const float*)d_in[3];
  const float* Wv     = (const float*)d_in[4];
  const float* Wk     = (const float*)d_in[5];
  const float* Wq     = (const float*)d_in[6];
  const float* Wo     = (const float*)d_in[7];
  const float* bo     = (const float*)d_in[8];
  float* out = (float*)d_out;

  const size_t MB = (size_t)1 << 20;
  char* w = (char*)d_ws;
  u16* xq  = (u16*)(w + 0 * MB);    // 4 MB  (dead after proj)
  u16* xk  = (u16*)(w + 4 * MB);    // 4 MB  (dead after proj)
  u16* xv  = (u16*)(w + 8 * MB);    // 4 MB  (dead after proj)
  u16* wqb = (u16*)(w + 12 * MB);   // 2 MB  (dead after proj)
  u16* wkb = (u16*)(w + 14 * MB);   // 2 MB  (dead after proj)
  u16* wvb = (u16*)(w + 16 * MB);   // 2 MB  (dead after proj)
  u16* wob = (u16*)(w + 18 * MB);   // 2 MB  (live to end)
  u16* Bb  = (u16*)(w + 20 * MB);   // 8 MB  fragment-swizzled bias bf16
  u16* Qh  = (u16*)(w + 28 * MB);   // 4 MB
  u16* Kh  = (u16*)(w + 32 * MB);   // 4 MB
  u16* Vth = (u16*)(w + 36 * MB);   // 4 MB  V^T [E][L]
  u16* AOb = (u16*)(w + 40 * MB);   // 4 MB
  float* lp = (float*)(w + 44 * MB);// 1 MB  (4 splits)
  u16* Op  = (u16*)(w + 48 * MB);   // 16 MB (4 splits x 4 MB)

  // 1) convert + bias fragment-swizzle + out prefill (2621440 threads)
  cvt_all<<<10240, 256, 0, stream>>>(query, keys, values, Wq, Wk, Wv, Wo, dist, bo,
                                     xq, xk, xv, wqb, wkb, wvb, wob, Bb, out);

  // 2) Q/K/V projections (z=2 -> V^T), 128x128 tiles
  dim3 gProj(E_DIM / TN, L_SEQ / TM, 3);
  gemm_pd<0><<<gProj, 256, 0, stream>>>(xq, wqb, Qh,
                                        xk, wkb, Kh,
                                        xv, wvb, Vth,
                                        L_SEQ, E_DIM, E_DIM);

  // 3) split-K flash attention, 128 q-rows/block (1024 blocks, 4/CU resident)
  dim3 gAttn(L_SEQ / 128, H_HEADS, KSPLIT);
  flash9<<<gAttn, 256, 0, stream>>>(Qh, Kh, Vth, Bb, Op, lp);

  // 4) merge partials -> bf16 AO
  merge_attn<<<(L_SEQ * E_DIM / 4) / 256, 256, 0, stream>>>(Op, lp, AOb);

  // 5) out += AO @ Wo^T, split-K=2, atomic f32 accumulate
  dim3 gOut(E_DIM / TN, L_SEQ / TM, OSPLIT);
  gemm_pd<2><<<gOut, 256, 0, stream>>>(AOb, wob, out,
                                       AOb, wob, out,
                                       AOb, wob, out,
                                       L_SEQ, E_DIM, E_DIM);
}

// Round 8
// 195.605 us; speedup vs baseline: 1.0118x; 1.0118x over previous
//
#include <hip/hip_runtime.h>

// ---------------------------------------------------------------------------
// SelfAttention, L=2048, E=1024, H=16, D=64. fp32 in/out, bf16 MFMA compute.
//   cvt_all   : f32->bf16 (q,k,v,W*) + bias pre-SWIZZLED to MFMA-D fragment
//               order + out=bo prefill (bias swizzle: 8x fewer L2
//               transactions; round-4 win).
//   gemm_pd<0,64>: Q,K,V projections, 128x64 tiles -> 768 blocks = 3/CU
//               EXACT (was 384 = 1.5/CU: half the CUs ran 2 serialized
//               blocks, half idled). z selects tensor; z=2 writes V^T.
//   flash8    : split-K flash, S^T softmax, register-resident P (r6 proven;
//               r7's 2-tile PV pipeline was null -> reverted).
//   merge_attn: sum 4 partials, divide, write bf16 AO
//   gemm_pd<2,64>: out += AO @ Wo^T, 128x64 tiles -> 512 blocks = 2/CU
//               (was 256 = 1/CU), split-K=2, unsafeAtomicAdd f32.
// LESSONS: (256,8) = 64-reg cap = spill storm (r5, 1.2GB scratch HBM).
// OSPLIT=4 = 4x atomic traffic = ~8-10us (r4/r6). Occupancy not the flash
// lever (r2); LDS-pipe (r3) and VMEM divergence (r4) were; chain-breaking
// inside flash is null (r7). Now: GEMM launch geometry.
// ---------------------------------------------------------------------------

#define L_SEQ 2048
#define E_DIM 1024
#define H_HEADS 16
#define D_HEAD 64
#define KSPLIT 4     // flash k-split (1024 blocks = 4/CU; reg-footprint cap)
#define OSPLIT 2     // out-proj k-split

typedef unsigned short u16;
typedef unsigned int u32;
typedef __attribute__((ext_vector_type(8))) short bf16x8;
typedef __attribute__((ext_vector_type(4))) short bf16x4;
typedef __attribute__((ext_vector_type(8))) unsigned short u16x8;
typedef __attribute__((ext_vector_type(4))) unsigned short u16x4;
typedef __attribute__((ext_vector_type(4))) float f32x4;

#define C_LOG2E_32 0.045084220027780106f   // log2(e)/32

__device__ __forceinline__ float bf2f(u16 u) {
  union { u32 i; float f; } v; v.i = ((u32)u) << 16; return v.f;
}
__device__ __forceinline__ u16 f2bf(float f) {
  union { float f; u32 i; } v; v.f = f;
  u32 u = v.i;
  u += 0x7FFFu + ((u >> 16) & 1u);   // RNE
  return (u16)(u >> 16);
}
// pack bf16(lo), bf16(hi) into one u32 (round-half-up; operands > 0)
__device__ __forceinline__ u32 pack_bf16_pair(float lo, float hi) {
  union { float f; u32 u; } a, b;
  a.f = lo; b.f = hi;
  return __builtin_amdgcn_perm(b.u + 0x8000u, a.u + 0x8000u, 0x07060302u);
}
// async global->LDS 16B/lane; LDS dest = (wave-uniform base) + lane*16
__device__ __forceinline__ void gload16(const u16* g, u16* l) {
  __builtin_amdgcn_global_load_lds(
      (const __attribute__((address_space(1))) u32*)g,
      (__attribute__((address_space(3))) u32*)l, 16, 0, 0);
}

// ---------------------------------------------------------------------------
// One-shot conversion + bias fragment-swizzle + out prefill.
// Bias: thread = (tile, lane); tile = l16*128 + q16; lane reads
// dist[q16*16+col][l16*16+quad*4..+3] (f32x4) and writes u16x4 at
// Bp[tile*256 + lane*4] -- exactly the 16x16x32 MFMA D-fragment order.
// ---------------------------------------------------------------------------
__global__ void cvt_all(const float* __restrict__ xq, const float* __restrict__ xk,
                        const float* __restrict__ xv,
                        const float* __restrict__ wq, const float* __restrict__ wk,
                        const float* __restrict__ wv, const float* __restrict__ wo,
                        const float* __restrict__ dist, const float* __restrict__ bo,
                        u16* oq, u16* ok, u16* ov,
                        u16* owq, u16* owk, u16* owv, u16* owo, u16* obias,
                        float* __restrict__ outp)
{
  size_t gid = (size_t)blockIdx.x * 256 + threadIdx.x;
  const size_t NQ = 262144;     // (L*E)/8
  const size_t NW = 131072;     // (E*E)/8
  const size_t DL2 = 1048576;   // (L*L)/4 bias quads
  const size_t FILL = DL2 + 3 * NQ + 4 * NW;   // 2359296

  if (gid < DL2) {              // bias: fragment-swizzled layout
    int tile = (int)(gid >> 6);
    int ln   = (int)(gid & 63);
    int l16  = tile >> 7;       // tile = l16*128 + q16  (L/16 = 128)
    int q16  = tile & 127;
    int qq = q16 * 16 + (ln & 15);
    int ll = l16 * 16 + (ln >> 4) * 4;
    f32x4 d4 = *(const f32x4*)&dist[(size_t)qq * L_SEQ + ll];
    u16x4 o4;
#pragma unroll
    for (int j = 0; j < 4; ++j) {
      float f = d4[j];
      f = (f == 0.f) ? 0.f : C_LOG2E_32 / (f + 1.f);
      o4[j] = f2bf(f);
    }
    *(u16x4*)&obias[(size_t)tile * 256 + ln * 4] = o4;
    return;
  }

  if (gid >= FILL) {            // out[q][:] = bo (out-proj accumulates on top)
    size_t off = (gid - FILL) * 8;
    int n = (int)(off & (E_DIM - 1));
    *(f32x4*)&outp[off] = *(const f32x4*)&bo[n];
    *(f32x4*)&outp[off + 4] = *(const f32x4*)&bo[n + 4];
    return;
  }

  size_t g = gid - DL2;
  const float* src; u16* dst; size_t off;
  if      (g <     NQ)           { src = xq;   dst = oq;    off = g; }
  else if (g < 2 * NQ)           { src = xk;   dst = ok;    off = g - NQ; }
  else if (g < 3 * NQ)           { src = xv;   dst = ov;    off = g - 2 * NQ; }
  else if (g < 3 * NQ + NW)      { src = wq;   dst = owq;   off = g - 3 * NQ; }
  else if (g < 3 * NQ + 2 * NW)  { src = wk;   dst = owk;   off = g - 3 * NQ - NW; }
  else if (g < 3 * NQ + 3 * NW)  { src = wv;   dst = owv;   off = g - 3 * NQ - 2 * NW; }
  else                           { src = wo;   dst = owo;   off = g - 3 * NQ - 3 * NW; }

  f32x4 v0 = *(const f32x4*)&src[off * 8];
  f32x4 v1 = *(const f32x4*)&src[off * 8 + 4];
  u16x8 o;
#pragma unroll
  for (int j = 0; j < 4; ++j) {
    o[j] = f2bf(v0[j]); o[j + 4] = f2bf(v1[j]);
  }
  *(u16x8*)&dst[off * 8] = o;
}

// ---------------------------------------------------------------------------
// NT GEMM, bf16, pipelined: C[M,N] = A[M,K]*B[N,K]^T.  TM=128, TN = TNP
// template param (128: 2x2 waves of 64x64; 64: 4x1 waves of 32x64 -- halves
// per-block work to double block count for exact CU fill).
// BK=32 double-buffered LDS, one barrier/iter, prefetch after barrier.
// LDS slot s of row r holds granule s^((r>>1)&3) (16-row-chunk image is
// identical for A and B, so frag reads share slot8 in both TNP modes).
// OUTMODE 0: triple (z selects A/B/C), bf16 out, z==2 writes C^T.
// OUTMODE 2: single tensor, z = K-split (K/OSPLIT each), f32 atomic-add out.
// ---------------------------------------------------------------------------
#define TM 128
#define BK 32

template<int OUTMODE, int TNP>
__global__ __launch_bounds__(256, 3) void gemm_pd(
    const u16* __restrict__ A0, const u16* __restrict__ B0, void* __restrict__ C0,
    const u16* __restrict__ A1, const u16* __restrict__ B1, void* __restrict__ C1,
    const u16* __restrict__ A2, const u16* __restrict__ B2, void* __restrict__ C2,
    int M, int N, int K)
{
  const u16* A; const u16* B; void* C;
  if (OUTMODE == 2)         { A = A0; B = B0; C = C0; }
  else if (blockIdx.z == 0) { A = A0; B = B0; C = C0; }
  else if (blockIdx.z == 1) { A = A1; B = B1; C = C1; }
  else                      { A = A2; B = B2; C = C2; }

  __shared__ __align__(16) u16 As[2][TM * BK];    // 8 KB per buf
  __shared__ __align__(16) u16 Bs[2][TNP * BK];   // 8 or 4 KB per buf

  constexpr int MI = (TNP == 128) ? 4 : 2;   // m-frags per wave

  const int m0 = blockIdx.y * TM;
  const int n0 = blockIdx.x * TNP;
  const int t = threadIdx.x;
  const int wave = t >> 6;
  const int lane = t & 63;
  const int quad = lane >> 4;
  const int col  = lane & 15;
  const int wm = (TNP == 128) ? (wave >> 1) * 64 : wave * 32;
  const int wn = (TNP == 128) ? (wave & 1) * 64 : 0;

  // staging: one gload16 covers 16 rows x 32 cols; lane -> row lane/4,
  // slot lane&3, global granule (lane&3)^((lane>>3)&3)
  const int sr = lane >> 2;
  const int sg = ((lane & 3) ^ ((lane >> 3) & 3)) * 8;
  const int bw = (TNP == 128) ? wave * 32 : wave * 16;   // B rows per wave
  const u16* gA = A + (size_t)(m0 + wave * 32 + sr) * K + sg;
  const u16* gB = B + (size_t)(n0 + bw + sr) * K + sg;
  const int loA0 = (wave * 32) * BK;
  const int loA1 = (wave * 32 + 16) * BK;
  const int loB0 = bw * BK;
  const int loB1 = (bw + 16) * BK;

  const int kbeg = (OUTMODE == 2) ? blockIdx.z * (K / OSPLIT) : 0;
  const int kend = (OUTMODE == 2) ? kbeg + K / OSPLIT : K;

  f32x4 acc[MI][4];
#pragma unroll
  for (int i = 0; i < MI; ++i)
#pragma unroll
    for (int j = 0; j < 4; ++j) acc[i][j] = (f32x4){0.f, 0.f, 0.f, 0.f};

  // prologue: stage first tile into buf 0
  gload16(gA + kbeg, &As[0][loA0]);
  gload16(gA + (size_t)16 * K + kbeg, &As[0][loA1]);
  gload16(gB + kbeg, &Bs[0][loB0]);
  if constexpr (TNP == 128)
    gload16(gB + (size_t)16 * K + kbeg, &Bs[0][loB1]);

  const int slot8 = (quad ^ ((col >> 1) & 3)) * 8;   // frag granule (swizzled)

  int buf = 0;
  for (int k0 = kbeg; k0 < kend; k0 += BK) {
    __syncthreads();   // tile(buf) visible; prev iter's LDS reads done
    int nk = k0 + BK;
    if (nk < kend) {   // prefetch next tile; in flight across whole compute
      gload16(gA + nk, &As[buf ^ 1][loA0]);
      gload16(gA + (size_t)16 * K + nk, &As[buf ^ 1][loA1]);
      gload16(gB + nk, &Bs[buf ^ 1][loB0]);
      if constexpr (TNP == 128)
        gload16(gB + (size_t)16 * K + nk, &Bs[buf ^ 1][loB1]);
    }

    bf16x8 af[MI], bfr[4];
#pragma unroll
    for (int i = 0; i < MI; ++i)
      af[i] = *(const bf16x8*)&As[buf][(wm + i * 16 + col) * BK + slot8];
#pragma unroll
    for (int j = 0; j < 4; ++j)
      bfr[j] = *(const bf16x8*)&Bs[buf][(wn + j * 16 + col) * BK + slot8];

#pragma unroll
    for (int i = 0; i < MI; ++i)
#pragma unroll
      for (int j = 0; j < 4; ++j)
        acc[i][j] = __builtin_amdgcn_mfma_f32_16x16x32_bf16(af[i], bfr[j], acc[i][j], 0, 0, 0);

    buf ^= 1;
  }

  const bool transC = (OUTMODE == 0) && (blockIdx.z == 2);
#pragma unroll
  for (int i = 0; i < MI; ++i) {
    int rowb = m0 + wm + i * 16 + quad * 4;
#pragma unroll
    for (int j = 0; j < 4; ++j) {
      int cn = n0 + wn + j * 16 + col;
      if (OUTMODE == 2) {
#pragma unroll
        for (int r = 0; r < 4; ++r)
          unsafeAtomicAdd(&((float*)C)[(size_t)(rowb + r) * N + cn], acc[i][j][r]);
      } else if (transC) {
        u16x4 pk;
#pragma unroll
        for (int r = 0; r < 4; ++r) pk[r] = f2bf(acc[i][j][r]);
        *(u16x4*)&((u16*)C)[(size_t)cn * M + rowb] = pk;   // C^T: 4 contiguous
      } else {
#pragma unroll
        for (int r = 0; r < 4; ++r)
          ((u16*)C)[(size_t)(rowb + r) * N + cn] = f2bf(acc[i][j][r]);
      }
    }
  }
}

// ---------------------------------------------------------------------------
// Split-K flash attention, S^T form, REGISTER-RESIDENT P, coalesced bias.
// 32 q/wave (2 strips of 16), 128 q/block, grid 16x16x4 = 1024 blocks (4/CU).
// __launch_bounds__(256,4): 128-reg budget/wave -> VGPR 56 + 32 acc, NO
// spills. (256,8) = 64-reg cap = scratch spill storm (round-5: 1.2GB HBM,
// 346us). S^T 16x16x32 MFMA out (lane: q=col, l=quad*4+r) -> exp -> pack
// bf16x4 == A-operand of mfma_f32_16x16x16bf16_1k -> PV from VGPRs, no P LDS.
// Bias: fragment-swizzled Bp, 512B contiguous per wave-load (round-4 win).
// LDS/block = Ks 8K + Vs 8K = 16KB.  (r7's 2-tile PV pipeline: null, removed)
// ---------------------------------------------------------------------------
#define FK 32

__global__ __launch_bounds__(256, 4) void flash8(
    const u16* __restrict__ Q, const u16* __restrict__ Kp,
    const u16* __restrict__ Vt, const u16* __restrict__ Bb,
    u16* __restrict__ Op, float* __restrict__ lp)
{
  __shared__ __align__(16) u16 Ks[2][FK * 64];      // K-tile [l][d], swizzled
  __shared__ __align__(16) u16 Vs[2][D_HEAD * FK];  // V^T tile [d][l], swizzled

  const int h  = blockIdx.y;
  const int q0 = blockIdx.x * 128;
  const int z  = blockIdx.z;
  const int hoff = h * D_HEAD;
  const int kbase = z * (L_SEQ / KSPLIT);
  const int NT = (L_SEQ / KSPLIT) / FK;   // 16 tiles
  const int t = threadIdx.x;
  const int wave = t >> 6;
  const int lane = t & 63;
  const int quad = lane >> 4;
  const int col  = lane & 15;

  // Q fragments per strip (B-operand of S^T: n = q = col, k = d)
  bf16x8 qf[2][2];
#pragma unroll
  for (int s = 0; s < 2; ++s) {
    const int qs = q0 + wave * 32 + s * 16;
    const u16* qrow = Q + (size_t)(qs + col) * E_DIM + hoff;
    qf[s][0] = *(const bf16x8*)(qrow + quad * 8);
    qf[s][1] = *(const bf16x8*)(qrow + 32 + quad * 8);
  }
  // bias tile indexing: q16 block of this wave's strips, lane elem offset
  const int qb0 = blockIdx.x * 8 + wave * 2;   // (q0 + wave*32)/16
  const int lb4 = lane * 4;

  // K staging: 32 rows x 8 granules; wave covers 8 rows.
  const int krow = wave * 8 + (lane >> 3);
  const int kg = ((lane & 7) ^ (lane >> 3)) * 8;
  const u16* gK = Kp + (size_t)krow * E_DIM + hoff + kg;
  // V staging: 64 rows x 4 granules; wave covers 16 rows.
  const int vrow = wave * 16 + (lane >> 2);
  const int vg = ((lane & 3) ^ ((lane >> 4) & 3)) * 8;
  const u16* gV = Vt + (size_t)(hoff + vrow) * L_SEQ + vg;

  float l_lane[2] = {0.f, 0.f};
  f32x4 oacc[2][4];
#pragma unroll
  for (int s = 0; s < 2; ++s)
#pragma unroll
    for (int td = 0; td < 4; ++td) oacc[s][td] = (f32x4){0.f, 0.f, 0.f, 0.f};

  // prologue: stage tile 0 + bias regs for tile 0
  gload16(gK + (size_t)kbase * E_DIM, &Ks[0][wave * 8 * 64]);
  gload16(gV + kbase, &Vs[0][wave * 16 * FK]);
  u16x4 bv[2][2], bn[2][2];
  {
    const int kb16 = kbase >> 4;
#pragma unroll
    for (int s = 0; s < 2; ++s) {
      bv[s][0] = *(const u16x4*)&Bb[((size_t)(kb16 + 0) * 128 + qb0 + s) * 256 + lb4];
      bv[s][1] = *(const u16x4*)&Bb[((size_t)(kb16 + 1) * 128 + qb0 + s) * 256 + lb4];
    }
  }

  const int ks0 = (quad ^ (col & 7)) * 8;          // K frag slots (swizzled)
  const int ks1 = ((quad + 4) ^ (col & 7)) * 8;
  // V frag: row d = td*16+col; slot = (tt*2+(quad>>1)) ^ ((col>>2)&3)
  const int vc2 = (col >> 2) & 3;
  const int vq1 = quad >> 1;
  const int vlo = (quad & 1) * 4;

  int buf = 0;
  for (int kt = 0; kt < NT; ++kt) {
    const int k0 = kbase + kt * FK;
    __syncthreads();   // tile(buf) visible; prev iter's LDS reads done
    if (kt + 1 < NT) { // prefetch next tile + next bias regs
      const int nk = k0 + FK;
      gload16(gK + (size_t)nk * E_DIM, &Ks[buf ^ 1][wave * 8 * 64]);
      gload16(gV + nk, &Vs[buf ^ 1][wave * 16 * FK]);
      const int nk16 = nk >> 4;
#pragma unroll
      for (int s = 0; s < 2; ++s) {
        bn[s][0] = *(const u16x4*)&Bb[((size_t)(nk16 + 0) * 128 + qb0 + s) * 256 + lb4];
        bn[s][1] = *(const u16x4*)&Bb[((size_t)(nk16 + 1) * 128 + qb0 + s) * 256 + lb4];
      }
    }
    const u16* Kb = &Ks[buf][0];
    const u16* Vb = &Vs[buf][0];

    // V fragments for this tile (shared by both strips): b64, conflict-free
    bf16x4 vf[2][4];
#pragma unroll
    for (int tt = 0; tt < 2; ++tt) {
      const int slot = (tt * 2 + vq1) ^ vc2;
#pragma unroll
      for (int td = 0; td < 4; ++td)
        vf[tt][td] = *(const bf16x4*)&Vb[(td * 16 + col) * FK + slot * 8 + vlo];
    }

    // S^T tiles: A = K-frag (m=l), B = Q-frag (n=q); D: l=quad*4+r, q=col
    // exp() results pack straight into the PV A-operand (bf16x4, reg-resident)
    bf16x4 pa[2][2];
#pragma unroll
    for (int tt = 0; tt < 2; ++tt) {
      const u16* kr = &Kb[(tt * 16 + col) * 64];
      bf16x8 kf0 = *(const bf16x8*)&kr[ks0];
      bf16x8 kf1 = *(const bf16x8*)&kr[ks1];
#pragma unroll
      for (int s = 0; s < 2; ++s) {
        f32x4 a = (f32x4){0.f, 0.f, 0.f, 0.f};
        a = __builtin_amdgcn_mfma_f32_16x16x32_bf16(kf0, qf[s][0], a, 0, 0, 0);
        a = __builtin_amdgcn_mfma_f32_16x16x32_bf16(kf1, qf[s][1], a, 0, 0, 0);
        float p[4];
#pragma unroll
        for (int r = 0; r < 4; ++r) {
          p[r] = __builtin_amdgcn_exp2f(fmaf(a[r], C_LOG2E_32, bf2f(bv[s][tt][r])));
          l_lane[s] += p[r];
        }
        union { u32 w[2]; bf16x4 v; } pk;
        pk.w[0] = pack_bf16_pair(p[0], p[1]);
        pk.w[1] = pack_bf16_pair(p[2], p[3]);
        pa[s][tt] = pk.v;
      }
    }

    // O += P V via K=16 MFMA: A = pa (m=q=col, k=l_local=quad*4+j),
    // B = vf (k=l_local, n=d=col). D layout == oacc layout (q=quad*4+r).
#pragma unroll
    for (int s = 0; s < 2; ++s)
#pragma unroll
      for (int td = 0; td < 4; ++td) {
        oacc[s][td] = __builtin_amdgcn_mfma_f32_16x16x16bf16_1k(
            pa[s][0], vf[0][td], oacc[s][td], 0, 0, 0);
        oacc[s][td] = __builtin_amdgcn_mfma_f32_16x16x16bf16_1k(
            pa[s][1], vf[1][td], oacc[s][td], 0, 0, 0);
      }

#pragma unroll
    for (int s = 0; s < 2; ++s) { bv[s][0] = bn[s][0]; bv[s][1] = bn[s][1]; }
    buf ^= 1;
  }

  // l reduction: lanes sharing (lane&15) hold partials across quads
#pragma unroll
  for (int s = 0; s < 2; ++s) {
    l_lane[s] += __shfl_xor(l_lane[s], 16);
    l_lane[s] += __shfl_xor(l_lane[s], 32);
    if (lane < 16)
      lp[((size_t)z * L_SEQ + q0 + wave * 32 + s * 16 + lane) * H_HEADS + h] = l_lane[s];
  }

#pragma unroll
  for (int s = 0; s < 2; ++s) {
    const int qrow_mine = q0 + wave * 32 + s * 16 + quad * 4;
#pragma unroll
    for (int td = 0; td < 4; ++td)
#pragma unroll
      for (int r = 0; r < 4; ++r)
        Op[((size_t)z * L_SEQ + qrow_mine + r) * E_DIM + hoff + td * 16 + col] = f2bf(oacc[s][td][r]);
  }
}

// ---------------------------------------------------------------------------
// Merge split-K partials: AO = (sum_s O_s) / (sum_s l_s), bf16 out.
// ---------------------------------------------------------------------------
__global__ void merge_attn(const u16* __restrict__ Op, const float* __restrict__ lp,
                           u16* __restrict__ AOb)
{
  size_t gid = (size_t)blockIdx.x * 256 + threadIdx.x;
  size_t idx = gid * 4;
  int q = (int)(idx >> 10);
  int e = (int)(idx & 1023);
  int h = e >> 6;
  float o[4] = {0.f, 0.f, 0.f, 0.f};
  float lsum = 0.f;
#pragma unroll
  for (int s = 0; s < KSPLIT; ++s) {
    u16x4 pv = *(const u16x4*)&Op[((size_t)s * L_SEQ + q) * E_DIM + e];
#pragma unroll
    for (int j = 0; j < 4; ++j) o[j] += bf2f(pv[j]);
    lsum += lp[((size_t)s * L_SEQ + q) * H_HEADS + h];
  }
  float inv = 1.f / lsum;
  u16x4 pk;
#pragma unroll
  for (int j = 0; j < 4; ++j) pk[j] = f2bf(o[j] * inv);
  *(u16x4*)&AOb[idx] = pk;
}

// ---------------------------------------------------------------------------
extern "C" void kernel_launch(void* const* d_in, const int* in_sizes, int n_in,
                              void* d_out, int out_size, void* d_ws, size_t ws_size,
                              hipStream_t stream)
{
  const float* values = (const float*)d_in[0];
  const float* keys   = (const float*)d_in[1];
  const float* query  = (const float*)d_in[2];
  const float* dist   = (const float*)d_in[3];
  const float* Wv     = (const float*)d_in[4];
  const float* Wk     = (const float*)d_in[5];
  const float* Wq     = (const float*)d_in[6];
  const float* Wo     = (const float*)d_in[7];
  const float* bo     = (const float*)d_in[8];
  float* out = (float*)d_out;

  const size_t MB = (size_t)1 << 20;
  char* w = (char*)d_ws;
  u16* xq  = (u16*)(w + 0 * MB);    // 4 MB  (dead after proj)
  u16* xk  = (u16*)(w + 4 * MB);    // 4 MB  (dead after proj)
  u16* xv  = (u16*)(w + 8 * MB);    // 4 MB  (dead after proj)
  u16* wqb = (u16*)(w + 12 * MB);   // 2 MB  (dead after proj)
  u16* wkb = (u16*)(w + 14 * MB);   // 2 MB  (dead after proj)
  u16* wvb = (u16*)(w + 16 * MB);   // 2 MB  (dead after proj)
  u16* wob = (u16*)(w + 18 * MB);   // 2 MB  (live to end)
  u16* Bb  = (u16*)(w + 20 * MB);   // 8 MB  fragment-swizzled bias bf16
  u16* Qh  = (u16*)(w + 28 * MB);   // 4 MB
  u16* Kh  = (u16*)(w + 32 * MB);   // 4 MB
  u16* Vth = (u16*)(w + 36 * MB);   // 4 MB  V^T [E][L]
  u16* AOb = (u16*)(w + 40 * MB);   // 4 MB
  float* lp = (float*)(w + 44 * MB);// 1 MB  (4 splits)
  u16* Op  = (u16*)(w + 48 * MB);   // 16 MB (4 splits x 4 MB)

  // 1) convert + bias fragment-swizzle + out prefill (2621440 threads)
  cvt_all<<<10240, 256, 0, stream>>>(query, keys, values, Wq, Wk, Wv, Wo, dist, bo,
                                     xq, xk, xv, wqb, wkb, wvb, wob, Bb, out);

  // 2) Q/K/V projections (z=2 -> V^T), 128x64 tiles: 768 blocks = 3/CU exact
  dim3 gProj(E_DIM / 64, L_SEQ / TM, 3);
  gemm_pd<0, 64><<<gProj, 256, 0, stream>>>(xq, wqb, Qh,
                                            xk, wkb, Kh,
                                            xv, wvb, Vth,
                                            L_SEQ, E_DIM, E_DIM);

  // 3) split-K flash attention, 128 q-rows/block (1024 blocks, 4/CU resident)
  dim3 gAttn(L_SEQ / 128, H_HEADS, KSPLIT);
  flash8<<<gAttn, 256, 0, stream>>>(Qh, Kh, Vth, Bb, Op, lp);

  // 4) merge partials -> bf16 AO
  merge_attn<<<(L_SEQ * E_DIM / 4) / 256, 256, 0, stream>>>(Op, lp, AOb);

  // 5) out += AO @ Wo^T, 128x64 tiles, split-K=2: 512 blocks = 2/CU
  dim3 gOut(E_DIM / 64, L_SEQ / TM, OSPLIT);
  gemm_pd<2, 64><<<gOut, 256, 0, stream>>>(AOb, wob, out,
                                           AOb, wob, out,
                                           AOb, wob, out,
                                           L_SEQ, E_DIM, E_DIM);
}